// Round 5
// baseline (925.313 us; speedup 1.0000x reference)
//
#include <hip/hip_runtime.h>

typedef _Float16 half8  __attribute__((ext_vector_type(8)));
typedef _Float16 half4v __attribute__((ext_vector_type(4)));
typedef float    f32x4  __attribute__((ext_vector_type(4)));

#define GAT_SLOPE 0.2f
#define N_SRC0 500000
#define N_DST0 65536
#define N_DST1 8192
#define E0 1048576
#define E1 131072
#define MAXSEG 2048

__device__ __forceinline__ float leaky(float x) { return x >= 0.f ? x : GAT_SLOPE * x; }

// out[k*4+h] = sum_d W[k*(4D) + h*D + d] * a[h*D + d]
__global__ void collapse_kernel(const float* __restrict__ W, const float* __restrict__ a,
                                float* __restrict__ out, int K, int D) {
  int i = blockIdx.x * 256 + threadIdx.x;
  if (i >= K * 4) return;
  int k = i >> 2, h = i & 3;
  int N = 4 * D;
  float s = 0.f;
  for (int d = 0; d < D; ++d) s += W[(size_t)k * N + h * D + d] * a[h * D + d];
  out[i] = s;
}

// WT[n*K+k] = (fp16)W[k*N+n]
__global__ void transposeW_kernel(const float* __restrict__ W, _Float16* __restrict__ WT,
                                  int K, int N) {
  int i = blockIdx.x * 256 + threadIdx.x;
  if (i >= N * K) return;
  int nrow = i / K, k = i - nrow * K;
  WT[i] = (_Float16)W[(size_t)k * N + nrow];
}

// BTs[n*1024 + h*256 + k] = (n<47) ? 0.25*Ws1[k*188 + h*47 + n] : 0   (64 x 1024)
__global__ void wstack_kernel(const float* __restrict__ W, _Float16* __restrict__ BTs) {
  int i = blockIdx.x * 256 + threadIdx.x;  // i < 64*1024
  int n = i >> 10, kk = i & 1023;
  int h = kk >> 8, k = kk & 255;
  BTs[i] = (n < 47) ? (_Float16)(0.25f * W[(size_t)k * 188 + h * 47 + n]) : (_Float16)0.f;
}

// WLR[n*K+k]: n<4 -> wl[k*4+n]; n in [4,8) -> wr[k*4+n-4]; else 0.  (16 x K fp16)
__global__ void wlr_stack_kernel(const float* __restrict__ wl, const float* __restrict__ wr,
                                 _Float16* __restrict__ out, int K) {
  int i = blockIdx.x * 256 + threadIdx.x;
  if (i >= 16 * K) return;
  int n = i / K, k = i - n * K;
  float v = 0.f;
  if (n < 4) v = wl[k * 4 + n];
  else if (n < 8) v = wr[k * 4 + n - 4];
  out[i] = (_Float16)v;
}

// seg[d] = first edge index with dst >= d ; seg[nseg] = E (dst sorted ascending)
__global__ void seg_starts_kernel(const int* __restrict__ dst, int E, int nseg,
                                  int* __restrict__ seg) {
  int i = blockIdx.x * 256 + threadIdx.x;
  if (i > E) return;
  int lo = (i == 0) ? 0 : dst[i - 1] + 1;
  int hi = (i == E) ? nseg : dst[i];
  for (int d = lo; d <= hi; ++d) seg[d] = i;
}

// streaming: x fp32 -> xh fp16 (global), + MFMA el0/er0 = x @ WLR0(128x16)
// block = 256 thr, 128 rows per block
__global__ __launch_bounds__(256) void cvt_elr_mfma_kernel(
    const float* __restrict__ x, const _Float16* __restrict__ WLR,
    _Float16* __restrict__ xh, float* __restrict__ el, float* __restrict__ er,
    int M, int n_dst) {
  __shared__ _Float16 As[128 * 128];
  const int t = threadIdx.x, lane = t & 63, wid = t >> 6;
  const int m0 = blockIdx.x * 128;
  for (int i = 0; i < 8; ++i) {
    int c = t + 256 * i;
    int row = c >> 4, j = c & 15;
    int gr = m0 + row;
    half8 va = {};
    if (gr < M) {
      float4 f0 = *(const float4*)(x + (size_t)gr * 128 + j * 8);
      float4 f1 = *(const float4*)(x + (size_t)gr * 128 + j * 8 + 4);
      va[0] = (_Float16)f0.x; va[1] = (_Float16)f0.y;
      va[2] = (_Float16)f0.z; va[3] = (_Float16)f0.w;
      va[4] = (_Float16)f1.x; va[5] = (_Float16)f1.y;
      va[6] = (_Float16)f1.z; va[7] = (_Float16)f1.w;
      *(half8*)(xh + (size_t)gr * 128 + j * 8) = va;
    }
    *(half8*)(&As[row * 128 + ((j ^ (row & 7)) << 3)]) = va;
  }
  half8 bf[4];
  for (int kc = 0; kc < 4; ++kc)
    bf[kc] = *(const half8*)(WLR + (lane & 15) * 128 + kc * 32 + (lane >> 4) * 8);
  __syncthreads();
  f32x4 acc[2] = {};
  for (int rt = 0; rt < 2; ++rt) {
    int row = (wid * 2 + rt) * 16 + (lane & 15);
    for (int kc = 0; kc < 4; ++kc) {
      int chunk = kc * 4 + (lane >> 4);
      half8 af = *(const half8*)(&As[row * 128 + ((chunk ^ (row & 7)) << 3)]);
      acc[rt] = __builtin_amdgcn_mfma_f32_16x16x32_f16(af, bf[kc], acc[rt], 0, 0, 0);
    }
  }
  int col = lane & 15, quad = lane >> 4;
  for (int rt = 0; rt < 2; ++rt)
    for (int r = 0; r < 4; ++r) {
      int row = m0 + (wid * 2 + rt) * 16 + quad * 4 + r;
      if (row < M) {
        if (col < 4) el[(size_t)row * 4 + col] = acc[rt][r];
        else if (col < 8 && row < n_dst) er[(size_t)row * 4 + col - 4] = acc[rt][r];
      }
    }
}

// el1/er1 = h0(65536x256 fp16) @ WLR1(256x16); 128 rows per block
__global__ __launch_bounds__(256) void el_er1_mfma_kernel(
    const _Float16* __restrict__ h0, const _Float16* __restrict__ WLR,
    float* __restrict__ el, float* __restrict__ er, int M, int n_dst) {
  __shared__ _Float16 As[128 * 128];
  const int t = threadIdx.x, lane = t & 63, wid = t >> 6;
  const int m0 = blockIdx.x * 128;
  f32x4 acc[2] = {};
  for (int k0 = 0; k0 < 256; k0 += 128) {
    for (int i = 0; i < 8; ++i) {
      int c = t + 256 * i, row = c >> 4, j = c & 15;
      *(half8*)(&As[row * 128 + ((j ^ (row & 7)) << 3)]) =
          *(const half8*)(h0 + (size_t)(m0 + row) * 256 + k0 + j * 8);
    }
    half8 bf[4];
    for (int kc = 0; kc < 4; ++kc)
      bf[kc] = *(const half8*)(WLR + (lane & 15) * 256 + k0 + kc * 32 + (lane >> 4) * 8);
    __syncthreads();
    for (int rt = 0; rt < 2; ++rt) {
      int row = (wid * 2 + rt) * 16 + (lane & 15);
      for (int kc = 0; kc < 4; ++kc) {
        int chunk = kc * 4 + (lane >> 4);
        half8 af = *(const half8*)(&As[row * 128 + ((chunk ^ (row & 7)) << 3)]);
        acc[rt] = __builtin_amdgcn_mfma_f32_16x16x32_f16(af, bf[kc], acc[rt], 0, 0, 0);
      }
    }
    __syncthreads();
  }
  int col = lane & 15, quad = lane >> 4;
  for (int rt = 0; rt < 2; ++rt)
    for (int r = 0; r < 4; ++r) {
      int row = m0 + (wid * 2 + rt) * 16 + quad * 4 + r;
      if (col < 4) el[(size_t)row * 4 + col] = acc[rt][r];
      else if (col < 8 && row < n_dst) er[(size_t)row * 4 + col - 4] = acc[rt][r];
    }
}

// layer-0 aggregation: axh[n][h][0:128] = (sum_e a_e[h] * xh[src_e]) / s[h]
// alpha cached in LDS; 128 thr/node.
__global__ __launch_bounds__(128) void agg0x_kernel(
    const int* __restrict__ src, const int* __restrict__ seg,
    const float* __restrict__ el, const float* __restrict__ er,
    const _Float16* __restrict__ xh, _Float16* __restrict__ axh) {
  int n = blockIdx.x;
  int t = threadIdx.x, lane = t & 63, w = t >> 6;
  __shared__ float ealf[MAXSEG * 4];
  __shared__ float wpart[8];
  __shared__ float part[512];
  int s0 = seg[n], s1 = seg[n + 1], len = s1 - s0;
  float4 erv = *(const float4*)(er + (size_t)n * 4);
  float m4[4] = {-1e30f, -1e30f, -1e30f, -1e30f};
  for (int i = s0 + t; i < s1; i += 128) {
    float4 e4 = *(const float4*)(el + (size_t)src[i] * 4);
    float e0 = leaky(e4.x + erv.x), e1 = leaky(e4.y + erv.y);
    float e2 = leaky(e4.z + erv.z), e3 = leaky(e4.w + erv.w);
    int idx = i - s0;
    if (idx < MAXSEG) {
      float4 st = {e0, e1, e2, e3};
      *(float4*)(&ealf[idx * 4]) = st;
    }
    m4[0] = fmaxf(m4[0], e0); m4[1] = fmaxf(m4[1], e1);
    m4[2] = fmaxf(m4[2], e2); m4[3] = fmaxf(m4[3], e3);
  }
#pragma unroll
  for (int off = 32; off; off >>= 1)
#pragma unroll
    for (int h = 0; h < 4; ++h) m4[h] = fmaxf(m4[h], __shfl_xor(m4[h], off));
  if (lane == 0)
#pragma unroll
    for (int h = 0; h < 4; ++h) wpart[w * 4 + h] = m4[h];
  __syncthreads();
  float gm[4];
#pragma unroll
  for (int h = 0; h < 4; ++h) gm[h] = fmaxf(wpart[h], wpart[4 + h]);
  float s4[4] = {};
  for (int idx = t; idx < len; idx += 128) {
    if (idx < MAXSEG) {
      float4 e4 = *(const float4*)(&ealf[idx * 4]);
      float a0 = __expf(e4.x - gm[0]), a1 = __expf(e4.y - gm[1]);
      float a2 = __expf(e4.z - gm[2]), a3 = __expf(e4.w - gm[3]);
      float4 st = {a0, a1, a2, a3};
      *(float4*)(&ealf[idx * 4]) = st;
      s4[0] += a0; s4[1] += a1; s4[2] += a2; s4[3] += a3;
    } else {
      float4 e4 = *(const float4*)(el + (size_t)src[s0 + idx] * 4);
      s4[0] += __expf(leaky(e4.x + erv.x) - gm[0]);
      s4[1] += __expf(leaky(e4.y + erv.y) - gm[1]);
      s4[2] += __expf(leaky(e4.z + erv.z) - gm[2]);
      s4[3] += __expf(leaky(e4.w + erv.w) - gm[3]);
    }
  }
#pragma unroll
  for (int off = 32; off; off >>= 1)
#pragma unroll
    for (int h = 0; h < 4; ++h) s4[h] += __shfl_xor(s4[h], off);
  __syncthreads();
  if (lane == 0)
#pragma unroll
    for (int h = 0; h < 4; ++h) wpart[w * 4 + h] = s4[h];
  __syncthreads();
  float sinv[4];
#pragma unroll
  for (int h = 0; h < 4; ++h) {
    float sv = wpart[h] + wpart[4 + h];
    sinv[h] = sv > 0.f ? 1.f / sv : 0.f;
  }
  int g = t >> 5, ci = t & 31;
  float A[4][4] = {};
  for (int i = s0 + g; i < s1; i += 4) {
    int idx = i - s0;
    float a0, a1, a2, a3;
    if (idx < MAXSEG) {
      float4 av = *(const float4*)(&ealf[idx * 4]);
      a0 = av.x; a1 = av.y; a2 = av.z; a3 = av.w;
    } else {
      float4 e4 = *(const float4*)(el + (size_t)src[i] * 4);
      a0 = __expf(leaky(e4.x + erv.x) - gm[0]);
      a1 = __expf(leaky(e4.y + erv.y) - gm[1]);
      a2 = __expf(leaky(e4.z + erv.z) - gm[2]);
      a3 = __expf(leaky(e4.w + erv.w) - gm[3]);
    }
    half4v xv = *(const half4v*)(xh + (size_t)src[i] * 128 + ci * 4);
#pragma unroll
    for (int c = 0; c < 4; ++c) {
      float xc = (float)xv[c];
      A[0][c] += a0 * xc; A[1][c] += a1 * xc; A[2][c] += a2 * xc; A[3][c] += a3 * xc;
    }
  }
#pragma unroll
  for (int h = 0; h < 4; ++h)
#pragma unroll
    for (int c = 0; c < 4; ++c) A[h][c] += __shfl_xor(A[h][c], 32);
  if (w == 1 && lane < 32)
#pragma unroll
    for (int h = 0; h < 4; ++h)
#pragma unroll
      for (int c = 0; c < 4; ++c) part[ci * 16 + h * 4 + c] = A[h][c];
  __syncthreads();
  if (w == 0 && lane < 32) {
#pragma unroll
    for (int h = 0; h < 4; ++h) {
      half4v o;
#pragma unroll
      for (int c = 0; c < 4; ++c)
        o[c] = (_Float16)((A[h][c] + part[ci * 16 + h * 4 + c]) * sinv[h]);
      *(half4v*)(axh + ((size_t)n * 4 + h) * 128 + ci * 4) = o;
    }
  }
}

// layer-1 aggregation: axh1[n][h][0:256] from h0 rows; same structure, 8 ch/lane
__global__ __launch_bounds__(128) void agg1x_kernel(
    const int* __restrict__ src, const int* __restrict__ seg,
    const float* __restrict__ el, const float* __restrict__ er,
    const _Float16* __restrict__ h0, _Float16* __restrict__ axh1) {
  int n = blockIdx.x;
  int t = threadIdx.x, lane = t & 63, w = t >> 6;
  __shared__ float ealf[MAXSEG * 4];
  __shared__ float wpart[8];
  __shared__ float part[1024];
  int s0 = seg[n], s1 = seg[n + 1], len = s1 - s0;
  float4 erv = *(const float4*)(er + (size_t)n * 4);
  float m4[4] = {-1e30f, -1e30f, -1e30f, -1e30f};
  for (int i = s0 + t; i < s1; i += 128) {
    float4 e4 = *(const float4*)(el + (size_t)src[i] * 4);
    float e0 = leaky(e4.x + erv.x), e1 = leaky(e4.y + erv.y);
    float e2 = leaky(e4.z + erv.z), e3 = leaky(e4.w + erv.w);
    int idx = i - s0;
    if (idx < MAXSEG) {
      float4 st = {e0, e1, e2, e3};
      *(float4*)(&ealf[idx * 4]) = st;
    }
    m4[0] = fmaxf(m4[0], e0); m4[1] = fmaxf(m4[1], e1);
    m4[2] = fmaxf(m4[2], e2); m4[3] = fmaxf(m4[3], e3);
  }
#pragma unroll
  for (int off = 32; off; off >>= 1)
#pragma unroll
    for (int h = 0; h < 4; ++h) m4[h] = fmaxf(m4[h], __shfl_xor(m4[h], off));
  if (lane == 0)
#pragma unroll
    for (int h = 0; h < 4; ++h) wpart[w * 4 + h] = m4[h];
  __syncthreads();
  float gm[4];
#pragma unroll
  for (int h = 0; h < 4; ++h) gm[h] = fmaxf(wpart[h], wpart[4 + h]);
  float s4[4] = {};
  for (int idx = t; idx < len; idx += 128) {
    if (idx < MAXSEG) {
      float4 e4 = *(const float4*)(&ealf[idx * 4]);
      float a0 = __expf(e4.x - gm[0]), a1 = __expf(e4.y - gm[1]);
      float a2 = __expf(e4.z - gm[2]), a3 = __expf(e4.w - gm[3]);
      float4 st = {a0, a1, a2, a3};
      *(float4*)(&ealf[idx * 4]) = st;
      s4[0] += a0; s4[1] += a1; s4[2] += a2; s4[3] += a3;
    } else {
      float4 e4 = *(const float4*)(el + (size_t)src[s0 + idx] * 4);
      s4[0] += __expf(leaky(e4.x + erv.x) - gm[0]);
      s4[1] += __expf(leaky(e4.y + erv.y) - gm[1]);
      s4[2] += __expf(leaky(e4.z + erv.z) - gm[2]);
      s4[3] += __expf(leaky(e4.w + erv.w) - gm[3]);
    }
  }
#pragma unroll
  for (int off = 32; off; off >>= 1)
#pragma unroll
    for (int h = 0; h < 4; ++h) s4[h] += __shfl_xor(s4[h], off);
  __syncthreads();
  if (lane == 0)
#pragma unroll
    for (int h = 0; h < 4; ++h) wpart[w * 4 + h] = s4[h];
  __syncthreads();
  float sinv[4];
#pragma unroll
  for (int h = 0; h < 4; ++h) {
    float sv = wpart[h] + wpart[4 + h];
    sinv[h] = sv > 0.f ? 1.f / sv : 0.f;
  }
  int g = t >> 5, ci = t & 31;
  float A[4][8] = {};
  for (int i = s0 + g; i < s1; i += 4) {
    int idx = i - s0;
    float a0, a1, a2, a3;
    if (idx < MAXSEG) {
      float4 av = *(const float4*)(&ealf[idx * 4]);
      a0 = av.x; a1 = av.y; a2 = av.z; a3 = av.w;
    } else {
      float4 e4 = *(const float4*)(el + (size_t)src[i] * 4);
      a0 = __expf(leaky(e4.x + erv.x) - gm[0]);
      a1 = __expf(leaky(e4.y + erv.y) - gm[1]);
      a2 = __expf(leaky(e4.z + erv.z) - gm[2]);
      a3 = __expf(leaky(e4.w + erv.w) - gm[3]);
    }
    half8 xv = *(const half8*)(h0 + (size_t)src[i] * 256 + ci * 8);
#pragma unroll
    for (int c = 0; c < 8; ++c) {
      float xc = (float)xv[c];
      A[0][c] += a0 * xc; A[1][c] += a1 * xc; A[2][c] += a2 * xc; A[3][c] += a3 * xc;
    }
  }
#pragma unroll
  for (int h = 0; h < 4; ++h)
#pragma unroll
    for (int c = 0; c < 8; ++c) A[h][c] += __shfl_xor(A[h][c], 32);
  if (w == 1 && lane < 32)
#pragma unroll
    for (int h = 0; h < 4; ++h)
#pragma unroll
      for (int c = 0; c < 8; ++c) part[ci * 32 + h * 8 + c] = A[h][c];
  __syncthreads();
  if (w == 0 && lane < 32) {
#pragma unroll
    for (int h = 0; h < 4; ++h) {
      half8 o;
#pragma unroll
      for (int c = 0; c < 8; ++c)
        o[c] = (_Float16)((A[h][c] + part[ci * 32 + h * 8 + c]) * sinv[h]);
      *(half8*)(axh1 + ((size_t)n * 4 + h) * 256 + ci * 8) = o;
    }
  }
}

// h0[m, h*64+d] = relu( axh[m,h,:] @ BT0[h*64+d, :] + b0 ), grid (4, 512)
__global__ __launch_bounds__(256) void gemm_h0_kernel(
    const _Float16* __restrict__ axh, const _Float16* __restrict__ BT,
    const float* __restrict__ b, _Float16* __restrict__ h0) {
  __shared__ _Float16 As[128 * 128];
  __shared__ _Float16 Bs[64 * 128];
  const int t = threadIdx.x, lane = t & 63, wid = t >> 6;
  const int h = blockIdx.x, m0 = blockIdx.y * 128;
  for (int i = 0; i < 8; ++i) {
    int c = t + 256 * i, row = c >> 4, j = c & 15;
    int sw = ((j ^ (row & 7)) << 3);
    *(half8*)(&As[row * 128 + sw]) =
        *(const half8*)(axh + ((size_t)(m0 + row) * 4 + h) * 128 + j * 8);
  }
  for (int i = 0; i < 4; ++i) {
    int c = t + 256 * i, row = c >> 4, j = c & 15;
    int sw = ((j ^ (row & 7)) << 3);
    *(half8*)(&Bs[row * 128 + sw]) =
        *(const half8*)(BT + (size_t)(h * 64 + row) * 128 + j * 8);
  }
  __syncthreads();
  const int wm = wid * 32;
  f32x4 acc[2][4] = {};
  for (int ks = 0; ks < 4; ++ks) {
    int kc = ks * 4 + (lane >> 4);
    half8 af[2], bf[4];
    for (int i = 0; i < 2; ++i) {
      int ra = wm + 16 * i + (lane & 15);
      af[i] = *(const half8*)(&As[ra * 128 + ((kc ^ (ra & 7)) << 3)]);
    }
    for (int j2 = 0; j2 < 4; ++j2) {
      int rb = 16 * j2 + (lane & 15);
      bf[j2] = *(const half8*)(&Bs[rb * 128 + ((kc ^ (rb & 7)) << 3)]);
    }
    for (int i = 0; i < 2; ++i)
      for (int j2 = 0; j2 < 4; ++j2)
        acc[i][j2] = __builtin_amdgcn_mfma_f32_16x16x32_f16(af[i], bf[j2], acc[i][j2], 0, 0, 0);
  }
  int quad = lane >> 4;
  for (int j2 = 0; j2 < 4; ++j2) {
    int gcol = h * 64 + 16 * j2 + (lane & 15);
    float bias = b[gcol];
    for (int i = 0; i < 2; ++i) {
      int r0 = m0 + wm + 16 * i + quad * 4;
      for (int r = 0; r < 4; ++r)
        h0[(size_t)(r0 + r) * 256 + gcol] = (_Float16)fmaxf(acc[i][j2][r] + bias, 0.f);
    }
  }
}

// out[m, 0:47] = log_softmax( axh1[m,:,:] (1024) @ BTs (1024 x 64, pre-scaled 0.25) + bmean )
__global__ __launch_bounds__(256) void gemm_out_kernel(
    const _Float16* __restrict__ axh1, const _Float16* __restrict__ BTs,
    const float* __restrict__ b1, float* __restrict__ out) {
  __shared__ _Float16 As[64 * 128];
  __shared__ _Float16 Bs[64 * 128];
  const int t = threadIdx.x, lane = t & 63, wid = t >> 6;
  const int m0 = blockIdx.x * 64;
  f32x4 acc[4] = {};
  for (int k0 = 0; k0 < 1024; k0 += 128) {
    for (int i = 0; i < 4; ++i) {
      int c = t + 256 * i, row = c >> 4, j = c & 15;
      int sw = ((j ^ (row & 7)) << 3);
      *(half8*)(&As[row * 128 + sw]) =
          *(const half8*)(axh1 + (size_t)(m0 + row) * 1024 + k0 + j * 8);
      *(half8*)(&Bs[row * 128 + sw]) =
          *(const half8*)(BTs + (size_t)row * 1024 + k0 + j * 8);
    }
    __syncthreads();
    const int wm = wid * 16;
    for (int ks = 0; ks < 4; ++ks) {
      int kc = ks * 4 + (lane >> 4);
      int ra = wm + (lane & 15);
      half8 af = *(const half8*)(&As[ra * 128 + ((kc ^ (ra & 7)) << 3)]);
      for (int j2 = 0; j2 < 4; ++j2) {
        int rb = 16 * j2 + (lane & 15);
        half8 bf = *(const half8*)(&Bs[rb * 128 + ((kc ^ (rb & 7)) << 3)]);
        acc[j2] = __builtin_amdgcn_mfma_f32_16x16x32_f16(af, bf, acc[j2], 0, 0, 0);
      }
    }
    __syncthreads();
  }
  int quad = lane >> 4, cl = lane & 15;
  float bm[3];
  for (int j2 = 0; j2 < 3; ++j2) {
    int col = 16 * j2 + cl;
    bm[j2] = (col < 47) ? 0.25f * (b1[col] + b1[col + 47] + b1[col + 94] + b1[col + 141]) : 0.f;
  }
  for (int r = 0; r < 4; ++r) {
    int row = m0 + wid * 16 + quad * 4 + r;
    float v[3];
    float mx = -1e30f;
    for (int j2 = 0; j2 < 3; ++j2) {
      int col = 16 * j2 + cl;
      v[j2] = acc[j2][r] + bm[j2];
      if (col < 47) mx = fmaxf(mx, v[j2]);
    }
    for (int off = 8; off; off >>= 1) mx = fmaxf(mx, __shfl_xor(mx, off));
    float s = 0.f;
    for (int j2 = 0; j2 < 3; ++j2) {
      int col = 16 * j2 + cl;
      if (col < 47) s += __expf(v[j2] - mx);
    }
    for (int off = 8; off; off >>= 1) s += __shfl_xor(s, off);
    float lse = mx + __logf(s);
    for (int j2 = 0; j2 < 3; ++j2) {
      int col = 16 * j2 + cl;
      if (col < 47) out[(size_t)row * 47 + col] = v[j2] - lse;
    }
  }
}

extern "C" void kernel_launch(void* const* d_in, const int* in_sizes, int n_in,
                              void* d_out, int out_size, void* d_ws, size_t ws_size,
                              hipStream_t stream) {
  const float* x   = (const float*)d_in[0];
  const int* src0  = (const int*)d_in[1];
  const int* dst0  = (const int*)d_in[2];
  const int* src1  = (const int*)d_in[3];
  const int* dst1  = (const int*)d_in[4];
  const float* Ws0 = (const float*)d_in[5];
  const float* Wd0 = (const float*)d_in[6];
  const float* al0 = (const float*)d_in[7];
  const float* ar0 = (const float*)d_in[8];
  const float* b0  = (const float*)d_in[9];
  const float* Ws1 = (const float*)d_in[10];
  const float* Wd1 = (const float*)d_in[11];
  const float* al1 = (const float*)d_in[12];
  const float* ar1 = (const float*)d_in[13];
  const float* b1  = (const float*)d_in[14];

  char* w = (char*)d_ws;
  auto alloc = [&](size_t bytes) {
    char* p = w;
    w += (bytes + 255) & ~(size_t)255;
    return p;
  };
  _Float16* xh   = (_Float16*)alloc((size_t)N_SRC0 * 128 * 2);   // 128 MB
  _Float16* axh  = (_Float16*)alloc((size_t)N_DST0 * 512 * 2);   // 67 MB
  _Float16* h0   = (_Float16*)alloc((size_t)N_DST0 * 256 * 2);   // 33.5 MB
  _Float16* axh1 = (_Float16*)alloc((size_t)N_DST1 * 1024 * 2);  // 16.8 MB
  float* el0     = (float*)alloc((size_t)N_SRC0 * 4 * 4);
  float* er0     = (float*)alloc((size_t)N_DST0 * 4 * 4);
  float* el1     = (float*)alloc((size_t)N_DST0 * 4 * 4);
  float* er1     = (float*)alloc((size_t)N_DST1 * 4 * 4);
  int* seg0      = (int*)alloc((size_t)(N_DST0 + 1) * 4);
  int* seg1      = (int*)alloc((size_t)(N_DST1 + 1) * 4);
  _Float16* BT0  = (_Float16*)alloc(256 * 128 * 2);
  _Float16* BTs  = (_Float16*)alloc(64 * 1024 * 2);
  _Float16* WLR0 = (_Float16*)alloc(16 * 128 * 2);
  _Float16* WLR1 = (_Float16*)alloc(16 * 256 * 2);
  float* wl0     = (float*)alloc(128 * 4 * 4);
  float* wr0     = (float*)alloc(128 * 4 * 4);
  float* wl1     = (float*)alloc(256 * 4 * 4);
  float* wr1     = (float*)alloc(256 * 4 * 4);

  collapse_kernel<<<2, 256, 0, stream>>>(Ws0, al0, wl0, 128, 64);
  collapse_kernel<<<2, 256, 0, stream>>>(Wd0, ar0, wr0, 128, 64);
  collapse_kernel<<<4, 256, 0, stream>>>(Ws1, al1, wl1, 256, 47);
  collapse_kernel<<<4, 256, 0, stream>>>(Wd1, ar1, wr1, 256, 47);
  wlr_stack_kernel<<<8, 256, 0, stream>>>(wl0, wr0, WLR0, 128);
  wlr_stack_kernel<<<16, 256, 0, stream>>>(wl1, wr1, WLR1, 256);
  transposeW_kernel<<<128, 256, 0, stream>>>(Ws0, BT0, 128, 256);
  wstack_kernel<<<256, 256, 0, stream>>>(Ws1, BTs);
  seg_starts_kernel<<<(E0 + 1 + 255) / 256, 256, 0, stream>>>(dst0, E0, N_DST0, seg0);
  seg_starts_kernel<<<(E1 + 1 + 255) / 256, 256, 0, stream>>>(dst1, E1, N_DST1, seg1);
  cvt_elr_mfma_kernel<<<(N_SRC0 + 127) / 128, 256, 0, stream>>>(x, WLR0, xh, el0, er0,
                                                                N_SRC0, N_DST0);
  agg0x_kernel<<<N_DST0, 128, 0, stream>>>(src0, seg0, el0, er0, xh, axh);
  gemm_h0_kernel<<<dim3(4, N_DST0 / 128), 256, 0, stream>>>(axh, BT0, b0, h0);
  el_er1_mfma_kernel<<<N_DST0 / 128, 256, 0, stream>>>(h0, WLR1, el1, er1, N_DST0, N_DST1);
  agg1x_kernel<<<N_DST1, 128, 0, stream>>>(src1, seg1, el1, er1, h0, axh1);
  gemm_out_kernel<<<N_DST1 / 64, 256, 0, stream>>>(axh1, BTs, b1, (float*)d_out);
}

// Round 6
// 642.747 us; speedup vs baseline: 1.4396x; 1.4396x over previous
//
#include <hip/hip_runtime.h>

typedef _Float16 half8  __attribute__((ext_vector_type(8)));
typedef _Float16 half4v __attribute__((ext_vector_type(4)));
typedef float    f32x4  __attribute__((ext_vector_type(4)));

#define GAT_SLOPE 0.2f
#define N_SRC0 500000
#define N_DST0 65536
#define N_DST1 8192
#define E0 1048576
#define E1 131072
#define MAXSEG 80   // avg deg = 16; Poisson tail @ 80 ~ 0. Fallback path covers overflow.

__device__ __forceinline__ float leaky(float x) { return x >= 0.f ? x : GAT_SLOPE * x; }

// out[k*4+h] = sum_d W[k*(4D) + h*D + d] * a[h*D + d]
__global__ void collapse_kernel(const float* __restrict__ W, const float* __restrict__ a,
                                float* __restrict__ out, int K, int D) {
  int i = blockIdx.x * 256 + threadIdx.x;
  if (i >= K * 4) return;
  int k = i >> 2, h = i & 3;
  int N = 4 * D;
  float s = 0.f;
  for (int d = 0; d < D; ++d) s += W[(size_t)k * N + h * D + d] * a[h * D + d];
  out[i] = s;
}

// WT[n*K+k] = (fp16)W[k*N+n]
__global__ void transposeW_kernel(const float* __restrict__ W, _Float16* __restrict__ WT,
                                  int K, int N) {
  int i = blockIdx.x * 256 + threadIdx.x;
  if (i >= N * K) return;
  int nrow = i / K, k = i - nrow * K;
  WT[i] = (_Float16)W[(size_t)k * N + nrow];
}

// BTs[n*1024 + h*256 + k] = (n<47) ? 0.25*Ws1[k*188 + h*47 + n] : 0   (64 x 1024)
__global__ void wstack_kernel(const float* __restrict__ W, _Float16* __restrict__ BTs) {
  int i = blockIdx.x * 256 + threadIdx.x;  // i < 64*1024
  int n = i >> 10, kk = i & 1023;
  int h = kk >> 8, k = kk & 255;
  BTs[i] = (n < 47) ? (_Float16)(0.25f * W[(size_t)k * 188 + h * 47 + n]) : (_Float16)0.f;
}

// WLR[n*K+k]: n<4 -> wl[k*4+n]; n in [4,8) -> wr[k*4+n-4]; else 0.  (16 x K fp16)
__global__ void wlr_stack_kernel(const float* __restrict__ wl, const float* __restrict__ wr,
                                 _Float16* __restrict__ out, int K) {
  int i = blockIdx.x * 256 + threadIdx.x;
  if (i >= 16 * K) return;
  int n = i / K, k = i - n * K;
  float v = 0.f;
  if (n < 4) v = wl[k * 4 + n];
  else if (n < 8) v = wr[k * 4 + n - 4];
  out[i] = (_Float16)v;
}

// seg[d] = first edge index with dst >= d ; seg[nseg] = E (dst sorted ascending)
__global__ void seg_starts_kernel(const int* __restrict__ dst, int E, int nseg,
                                  int* __restrict__ seg) {
  int i = blockIdx.x * 256 + threadIdx.x;
  if (i > E) return;
  int lo = (i == 0) ? 0 : dst[i - 1] + 1;
  int hi = (i == E) ? nseg : dst[i];
  for (int d = lo; d <= hi; ++d) seg[d] = i;
}

// streaming: x fp32 -> xh fp16 (global), + MFMA el0/er0 = x @ WLR0(128x16)
__global__ __launch_bounds__(256) void cvt_elr_mfma_kernel(
    const float* __restrict__ x, const _Float16* __restrict__ WLR,
    _Float16* __restrict__ xh, float* __restrict__ el, float* __restrict__ er,
    int M, int n_dst) {
  __shared__ _Float16 As[128 * 128];
  const int t = threadIdx.x, lane = t & 63, wid = t >> 6;
  const int m0 = blockIdx.x * 128;
  for (int i = 0; i < 8; ++i) {
    int c = t + 256 * i;
    int row = c >> 4, j = c & 15;
    int gr = m0 + row;
    half8 va = {};
    if (gr < M) {
      float4 f0 = *(const float4*)(x + (size_t)gr * 128 + j * 8);
      float4 f1 = *(const float4*)(x + (size_t)gr * 128 + j * 8 + 4);
      va[0] = (_Float16)f0.x; va[1] = (_Float16)f0.y;
      va[2] = (_Float16)f0.z; va[3] = (_Float16)f0.w;
      va[4] = (_Float16)f1.x; va[5] = (_Float16)f1.y;
      va[6] = (_Float16)f1.z; va[7] = (_Float16)f1.w;
      *(half8*)(xh + (size_t)gr * 128 + j * 8) = va;
    }
    *(half8*)(&As[row * 128 + ((j ^ (row & 7)) << 3)]) = va;
  }
  half8 bf[4];
  for (int kc = 0; kc < 4; ++kc)
    bf[kc] = *(const half8*)(WLR + (lane & 15) * 128 + kc * 32 + (lane >> 4) * 8);
  __syncthreads();
  f32x4 acc[2] = {};
  for (int rt = 0; rt < 2; ++rt) {
    int row = (wid * 2 + rt) * 16 + (lane & 15);
    for (int kc = 0; kc < 4; ++kc) {
      int chunk = kc * 4 + (lane >> 4);
      half8 af = *(const half8*)(&As[row * 128 + ((chunk ^ (row & 7)) << 3)]);
      acc[rt] = __builtin_amdgcn_mfma_f32_16x16x32_f16(af, bf[kc], acc[rt], 0, 0, 0);
    }
  }
  int col = lane & 15, quad = lane >> 4;
  for (int rt = 0; rt < 2; ++rt)
    for (int r = 0; r < 4; ++r) {
      int row = m0 + (wid * 2 + rt) * 16 + quad * 4 + r;
      if (row < M) {
        if (col < 4) el[(size_t)row * 4 + col] = acc[rt][r];
        else if (col < 8 && row < n_dst) er[(size_t)row * 4 + col - 4] = acc[rt][r];
      }
    }
}

// el1/er1 = h0(65536x256 fp16) @ WLR1(256x16); 128 rows per block
__global__ __launch_bounds__(256) void el_er1_mfma_kernel(
    const _Float16* __restrict__ h0, const _Float16* __restrict__ WLR,
    float* __restrict__ el, float* __restrict__ er, int M, int n_dst) {
  __shared__ _Float16 As[128 * 128];
  const int t = threadIdx.x, lane = t & 63, wid = t >> 6;
  const int m0 = blockIdx.x * 128;
  f32x4 acc[2] = {};
  for (int k0 = 0; k0 < 256; k0 += 128) {
    for (int i = 0; i < 8; ++i) {
      int c = t + 256 * i, row = c >> 4, j = c & 15;
      *(half8*)(&As[row * 128 + ((j ^ (row & 7)) << 3)]) =
          *(const half8*)(h0 + (size_t)(m0 + row) * 256 + k0 + j * 8);
    }
    half8 bf[4];
    for (int kc = 0; kc < 4; ++kc)
      bf[kc] = *(const half8*)(WLR + (lane & 15) * 256 + k0 + kc * 32 + (lane >> 4) * 8);
    __syncthreads();
    for (int rt = 0; rt < 2; ++rt) {
      int row = (wid * 2 + rt) * 16 + (lane & 15);
      for (int kc = 0; kc < 4; ++kc) {
        int chunk = kc * 4 + (lane >> 4);
        half8 af = *(const half8*)(&As[row * 128 + ((chunk ^ (row & 7)) << 3)]);
        acc[rt] = __builtin_amdgcn_mfma_f32_16x16x32_f16(af, bf[kc], acc[rt], 0, 0, 0);
      }
    }
    __syncthreads();
  }
  int col = lane & 15, quad = lane >> 4;
  for (int rt = 0; rt < 2; ++rt)
    for (int r = 0; r < 4; ++r) {
      int row = m0 + (wid * 2 + rt) * 16 + quad * 4 + r;
      if (col < 4) el[(size_t)row * 4 + col] = acc[rt][r];
      else if (col < 8 && row < n_dst) er[(size_t)row * 4 + col - 4] = acc[rt][r];
    }
}

// layer-0 aggregation: axh[n][h][0:128] = (sum_e a_e[h] * xh[src_e]) / s[h]
// SoA score planes + src cache in small LDS (<4.5 KB); 128 thr/node.
__global__ __launch_bounds__(128) void agg0x_kernel(
    const int* __restrict__ src, const int* __restrict__ seg,
    const float* __restrict__ el, const float* __restrict__ er,
    const _Float16* __restrict__ xh, _Float16* __restrict__ axh) {
  int n = blockIdx.x;
  int t = threadIdx.x, lane = t & 63, w = t >> 6;
  __shared__ float sc[4][MAXSEG];
  __shared__ int sid[MAXSEG];
  __shared__ float wpart[8];
  __shared__ float part[512];
  int s0 = seg[n], s1 = seg[n + 1], len = s1 - s0;
  float4 erv = *(const float4*)(er + (size_t)n * 4);
  float m4[4] = {-1e30f, -1e30f, -1e30f, -1e30f};
  for (int idx = t; idx < len; idx += 128) {
    int sidx = src[s0 + idx];
    float4 e4 = *(const float4*)(el + (size_t)sidx * 4);
    float e0 = leaky(e4.x + erv.x), e1 = leaky(e4.y + erv.y);
    float e2 = leaky(e4.z + erv.z), e3 = leaky(e4.w + erv.w);
    if (idx < MAXSEG) {
      sc[0][idx] = e0; sc[1][idx] = e1; sc[2][idx] = e2; sc[3][idx] = e3;
      sid[idx] = sidx;
    }
    m4[0] = fmaxf(m4[0], e0); m4[1] = fmaxf(m4[1], e1);
    m4[2] = fmaxf(m4[2], e2); m4[3] = fmaxf(m4[3], e3);
  }
#pragma unroll
  for (int off = 32; off; off >>= 1)
#pragma unroll
    for (int h = 0; h < 4; ++h) m4[h] = fmaxf(m4[h], __shfl_xor(m4[h], off));
  if (lane == 0)
#pragma unroll
    for (int h = 0; h < 4; ++h) wpart[w * 4 + h] = m4[h];
  __syncthreads();
  float gm[4];
#pragma unroll
  for (int h = 0; h < 4; ++h) gm[h] = fmaxf(wpart[h], wpart[4 + h]);
  float s4[4] = {};
  for (int idx = t; idx < len; idx += 128) {
    if (idx < MAXSEG) {
      float a0 = __expf(sc[0][idx] - gm[0]), a1 = __expf(sc[1][idx] - gm[1]);
      float a2 = __expf(sc[2][idx] - gm[2]), a3 = __expf(sc[3][idx] - gm[3]);
      sc[0][idx] = a0; sc[1][idx] = a1; sc[2][idx] = a2; sc[3][idx] = a3;
      s4[0] += a0; s4[1] += a1; s4[2] += a2; s4[3] += a3;
    } else {
      float4 e4 = *(const float4*)(el + (size_t)src[s0 + idx] * 4);
      s4[0] += __expf(leaky(e4.x + erv.x) - gm[0]);
      s4[1] += __expf(leaky(e4.y + erv.y) - gm[1]);
      s4[2] += __expf(leaky(e4.z + erv.z) - gm[2]);
      s4[3] += __expf(leaky(e4.w + erv.w) - gm[3]);
    }
  }
#pragma unroll
  for (int off = 32; off; off >>= 1)
#pragma unroll
    for (int h = 0; h < 4; ++h) s4[h] += __shfl_xor(s4[h], off);
  __syncthreads();
  if (lane == 0)
#pragma unroll
    for (int h = 0; h < 4; ++h) wpart[w * 4 + h] = s4[h];
  __syncthreads();
  float sinv[4];
#pragma unroll
  for (int h = 0; h < 4; ++h) {
    float sv = wpart[h] + wpart[4 + h];
    sinv[h] = sv > 0.f ? 1.f / sv : 0.f;
  }
  int g = t >> 5, ci = t & 31;
  float A[4][4] = {};
  for (int idx = g; idx < len; idx += 4) {
    float a0, a1, a2, a3;
    int sidx;
    if (idx < MAXSEG) {
      a0 = sc[0][idx]; a1 = sc[1][idx]; a2 = sc[2][idx]; a3 = sc[3][idx];
      sidx = sid[idx];
    } else {
      sidx = src[s0 + idx];
      float4 e4 = *(const float4*)(el + (size_t)sidx * 4);
      a0 = __expf(leaky(e4.x + erv.x) - gm[0]);
      a1 = __expf(leaky(e4.y + erv.y) - gm[1]);
      a2 = __expf(leaky(e4.z + erv.z) - gm[2]);
      a3 = __expf(leaky(e4.w + erv.w) - gm[3]);
    }
    half4v xv = *(const half4v*)(xh + (size_t)sidx * 128 + ci * 4);
#pragma unroll
    for (int c = 0; c < 4; ++c) {
      float xc = (float)xv[c];
      A[0][c] += a0 * xc; A[1][c] += a1 * xc; A[2][c] += a2 * xc; A[3][c] += a3 * xc;
    }
  }
#pragma unroll
  for (int h = 0; h < 4; ++h)
#pragma unroll
    for (int c = 0; c < 4; ++c) A[h][c] += __shfl_xor(A[h][c], 32);
  if (w == 1 && lane < 32)
#pragma unroll
    for (int h = 0; h < 4; ++h)
#pragma unroll
      for (int c = 0; c < 4; ++c) part[ci * 16 + h * 4 + c] = A[h][c];
  __syncthreads();
  if (w == 0 && lane < 32) {
#pragma unroll
    for (int h = 0; h < 4; ++h) {
      half4v o;
#pragma unroll
      for (int c = 0; c < 4; ++c)
        o[c] = (_Float16)((A[h][c] + part[ci * 16 + h * 4 + c]) * sinv[h]);
      *(half4v*)(axh + ((size_t)n * 4 + h) * 128 + ci * 4) = o;
    }
  }
}

// layer-1 aggregation: axh1[n][h][0:256] from h0 rows; same structure, 8 ch/lane
__global__ __launch_bounds__(128) void agg1x_kernel(
    const int* __restrict__ src, const int* __restrict__ seg,
    const float* __restrict__ el, const float* __restrict__ er,
    const _Float16* __restrict__ h0, _Float16* __restrict__ axh1) {
  int n = blockIdx.x;
  int t = threadIdx.x, lane = t & 63, w = t >> 6;
  __shared__ float sc[4][MAXSEG];
  __shared__ int sid[MAXSEG];
  __shared__ float wpart[8];
  __shared__ float part[1024];
  int s0 = seg[n], s1 = seg[n + 1], len = s1 - s0;
  float4 erv = *(const float4*)(er + (size_t)n * 4);
  float m4[4] = {-1e30f, -1e30f, -1e30f, -1e30f};
  for (int idx = t; idx < len; idx += 128) {
    int sidx = src[s0 + idx];
    float4 e4 = *(const float4*)(el + (size_t)sidx * 4);
    float e0 = leaky(e4.x + erv.x), e1 = leaky(e4.y + erv.y);
    float e2 = leaky(e4.z + erv.z), e3 = leaky(e4.w + erv.w);
    if (idx < MAXSEG) {
      sc[0][idx] = e0; sc[1][idx] = e1; sc[2][idx] = e2; sc[3][idx] = e3;
      sid[idx] = sidx;
    }
    m4[0] = fmaxf(m4[0], e0); m4[1] = fmaxf(m4[1], e1);
    m4[2] = fmaxf(m4[2], e2); m4[3] = fmaxf(m4[3], e3);
  }
#pragma unroll
  for (int off = 32; off; off >>= 1)
#pragma unroll
    for (int h = 0; h < 4; ++h) m4[h] = fmaxf(m4[h], __shfl_xor(m4[h], off));
  if (lane == 0)
#pragma unroll
    for (int h = 0; h < 4; ++h) wpart[w * 4 + h] = m4[h];
  __syncthreads();
  float gm[4];
#pragma unroll
  for (int h = 0; h < 4; ++h) gm[h] = fmaxf(wpart[h], wpart[4 + h]);
  float s4[4] = {};
  for (int idx = t; idx < len; idx += 128) {
    if (idx < MAXSEG) {
      float a0 = __expf(sc[0][idx] - gm[0]), a1 = __expf(sc[1][idx] - gm[1]);
      float a2 = __expf(sc[2][idx] - gm[2]), a3 = __expf(sc[3][idx] - gm[3]);
      sc[0][idx] = a0; sc[1][idx] = a1; sc[2][idx] = a2; sc[3][idx] = a3;
      s4[0] += a0; s4[1] += a1; s4[2] += a2; s4[3] += a3;
    } else {
      float4 e4 = *(const float4*)(el + (size_t)src[s0 + idx] * 4);
      s4[0] += __expf(leaky(e4.x + erv.x) - gm[0]);
      s4[1] += __expf(leaky(e4.y + erv.y) - gm[1]);
      s4[2] += __expf(leaky(e4.z + erv.z) - gm[2]);
      s4[3] += __expf(leaky(e4.w + erv.w) - gm[3]);
    }
  }
#pragma unroll
  for (int off = 32; off; off >>= 1)
#pragma unroll
    for (int h = 0; h < 4; ++h) s4[h] += __shfl_xor(s4[h], off);
  __syncthreads();
  if (lane == 0)
#pragma unroll
    for (int h = 0; h < 4; ++h) wpart[w * 4 + h] = s4[h];
  __syncthreads();
  float sinv[4];
#pragma unroll
  for (int h = 0; h < 4; ++h) {
    float sv = wpart[h] + wpart[4 + h];
    sinv[h] = sv > 0.f ? 1.f / sv : 0.f;
  }
  int g = t >> 5, ci = t & 31;
  float A[4][8] = {};
  for (int idx = g; idx < len; idx += 4) {
    float a0, a1, a2, a3;
    int sidx;
    if (idx < MAXSEG) {
      a0 = sc[0][idx]; a1 = sc[1][idx]; a2 = sc[2][idx]; a3 = sc[3][idx];
      sidx = sid[idx];
    } else {
      sidx = src[s0 + idx];
      float4 e4 = *(const float4*)(el + (size_t)sidx * 4);
      a0 = __expf(leaky(e4.x + erv.x) - gm[0]);
      a1 = __expf(leaky(e4.y + erv.y) - gm[1]);
      a2 = __expf(leaky(e4.z + erv.z) - gm[2]);
      a3 = __expf(leaky(e4.w + erv.w) - gm[3]);
    }
    half8 xv = *(const half8*)(h0 + (size_t)sidx * 256 + ci * 8);
#pragma unroll
    for (int c = 0; c < 8; ++c) {
      float xc = (float)xv[c];
      A[0][c] += a0 * xc; A[1][c] += a1 * xc; A[2][c] += a2 * xc; A[3][c] += a3 * xc;
    }
  }
#pragma unroll
  for (int h = 0; h < 4; ++h)
#pragma unroll
    for (int c = 0; c < 8; ++c) A[h][c] += __shfl_xor(A[h][c], 32);
  if (w == 1 && lane < 32)
#pragma unroll
    for (int h = 0; h < 4; ++h)
#pragma unroll
      for (int c = 0; c < 8; ++c) part[ci * 32 + h * 8 + c] = A[h][c];
  __syncthreads();
  if (w == 0 && lane < 32) {
#pragma unroll
    for (int h = 0; h < 4; ++h) {
      half8 o;
#pragma unroll
      for (int c = 0; c < 8; ++c)
        o[c] = (_Float16)((A[h][c] + part[ci * 32 + h * 8 + c]) * sinv[h]);
      *(half8*)(axh1 + ((size_t)n * 4 + h) * 256 + ci * 8) = o;
    }
  }
}

// h0[m, h*64+d] = relu( axh[m,h,:] @ BT0[h*64+d, :] + b0 ), grid (4, 512)
__global__ __launch_bounds__(256) void gemm_h0_kernel(
    const _Float16* __restrict__ axh, const _Float16* __restrict__ BT,
    const float* __restrict__ b, _Float16* __restrict__ h0) {
  __shared__ _Float16 As[128 * 128];
  __shared__ _Float16 Bs[64 * 128];
  const int t = threadIdx.x, lane = t & 63, wid = t >> 6;
  const int h = blockIdx.x, m0 = blockIdx.y * 128;
  for (int i = 0; i < 8; ++i) {
    int c = t + 256 * i, row = c >> 4, j = c & 15;
    int sw = ((j ^ (row & 7)) << 3);
    *(half8*)(&As[row * 128 + sw]) =
        *(const half8*)(axh + ((size_t)(m0 + row) * 4 + h) * 128 + j * 8);
  }
  for (int i = 0; i < 4; ++i) {
    int c = t + 256 * i, row = c >> 4, j = c & 15;
    int sw = ((j ^ (row & 7)) << 3);
    *(half8*)(&Bs[row * 128 + sw]) =
        *(const half8*)(BT + (size_t)(h * 64 + row) * 128 + j * 8);
  }
  __syncthreads();
  const int wm = wid * 32;
  f32x4 acc[2][4] = {};
  for (int ks = 0; ks < 4; ++ks) {
    int kc = ks * 4 + (lane >> 4);
    half8 af[2], bf[4];
    for (int i = 0; i < 2; ++i) {
      int ra = wm + 16 * i + (lane & 15);
      af[i] = *(const half8*)(&As[ra * 128 + ((kc ^ (ra & 7)) << 3)]);
    }
    for (int j2 = 0; j2 < 4; ++j2) {
      int rb = 16 * j2 + (lane & 15);
      bf[j2] = *(const half8*)(&Bs[rb * 128 + ((kc ^ (rb & 7)) << 3)]);
    }
    for (int i = 0; i < 2; ++i)
      for (int j2 = 0; j2 < 4; ++j2)
        acc[i][j2] = __builtin_amdgcn_mfma_f32_16x16x32_f16(af[i], bf[j2], acc[i][j2], 0, 0, 0);
  }
  int quad = lane >> 4;
  for (int j2 = 0; j2 < 4; ++j2) {
    int gcol = h * 64 + 16 * j2 + (lane & 15);
    float bias = b[gcol];
    for (int i = 0; i < 2; ++i) {
      int r0 = m0 + wm + 16 * i + quad * 4;
      for (int r = 0; r < 4; ++r)
        h0[(size_t)(r0 + r) * 256 + gcol] = (_Float16)fmaxf(acc[i][j2][r] + bias, 0.f);
    }
  }
}

// out[m, 0:47] = log_softmax( axh1[m,:,:] (1024) @ BTs (1024 x 64, pre-scaled 0.25) + bmean )
__global__ __launch_bounds__(256) void gemm_out_kernel(
    const _Float16* __restrict__ axh1, const _Float16* __restrict__ BTs,
    const float* __restrict__ b1, float* __restrict__ out) {
  __shared__ _Float16 As[64 * 128];
  __shared__ _Float16 Bs[64 * 128];
  const int t = threadIdx.x, lane = t & 63, wid = t >> 6;
  const int m0 = blockIdx.x * 64;
  f32x4 acc[4] = {};
  for (int k0 = 0; k0 < 1024; k0 += 128) {
    for (int i = 0; i < 4; ++i) {
      int c = t + 256 * i, row = c >> 4, j = c & 15;
      int sw = ((j ^ (row & 7)) << 3);
      *(half8*)(&As[row * 128 + sw]) =
          *(const half8*)(axh1 + (size_t)(m0 + row) * 1024 + k0 + j * 8);
      *(half8*)(&Bs[row * 128 + sw]) =
          *(const half8*)(BTs + (size_t)row * 1024 + k0 + j * 8);
    }
    __syncthreads();
    const int wm = wid * 16;
    for (int ks = 0; ks < 4; ++ks) {
      int kc = ks * 4 + (lane >> 4);
      int ra = wm + (lane & 15);
      half8 af = *(const half8*)(&As[ra * 128 + ((kc ^ (ra & 7)) << 3)]);
      for (int j2 = 0; j2 < 4; ++j2) {
        int rb = 16 * j2 + (lane & 15);
        half8 bf = *(const half8*)(&Bs[rb * 128 + ((kc ^ (rb & 7)) << 3)]);
        acc[j2] = __builtin_amdgcn_mfma_f32_16x16x32_f16(af, bf, acc[j2], 0, 0, 0);
      }
    }
    __syncthreads();
  }
  int quad = lane >> 4, cl = lane & 15;
  float bm[3];
  for (int j2 = 0; j2 < 3; ++j2) {
    int col = 16 * j2 + cl;
    bm[j2] = (col < 47) ? 0.25f * (b1[col] + b1[col + 47] + b1[col + 94] + b1[col + 141]) : 0.f;
  }
  for (int r = 0; r < 4; ++r) {
    int row = m0 + wid * 16 + quad * 4 + r;
    float v[3];
    float mx = -1e30f;
    for (int j2 = 0; j2 < 3; ++j2) {
      int col = 16 * j2 + cl;
      v[j2] = acc[j2][r] + bm[j2];
      if (col < 47) mx = fmaxf(mx, v[j2]);
    }
    for (int off = 8; off; off >>= 1) mx = fmaxf(mx, __shfl_xor(mx, off));
    float s = 0.f;
    for (int j2 = 0; j2 < 3; ++j2) {
      int col = 16 * j2 + cl;
      if (col < 47) s += __expf(v[j2] - mx);
    }
    for (int off = 8; off; off >>= 1) s += __shfl_xor(s, off);
    float lse = mx + __logf(s);
    for (int j2 = 0; j2 < 3; ++j2) {
      int col = 16 * j2 + cl;
      if (col < 47) out[(size_t)row * 47 + col] = v[j2] - lse;
    }
  }
}

extern "C" void kernel_launch(void* const* d_in, const int* in_sizes, int n_in,
                              void* d_out, int out_size, void* d_ws, size_t ws_size,
                              hipStream_t stream) {
  const float* x   = (const float*)d_in[0];
  const int* src0  = (const int*)d_in[1];
  const int* dst0  = (const int*)d_in[2];
  const int* src1  = (const int*)d_in[3];
  const int* dst1  = (const int*)d_in[4];
  const float* Ws0 = (const float*)d_in[5];
  const float* Wd0 = (const float*)d_in[6];
  const float* al0 = (const float*)d_in[7];
  const float* ar0 = (const float*)d_in[8];
  const float* b0  = (const float*)d_in[9];
  const float* Ws1 = (const float*)d_in[10];
  const float* Wd1 = (const float*)d_in[11];
  const float* al1 = (const float*)d_in[12];
  const float* ar1 = (const float*)d_in[13];
  const float* b1  = (const float*)d_in[14];

  char* w = (char*)d_ws;
  auto alloc = [&](size_t bytes) {
    char* p = w;
    w += (bytes + 255) & ~(size_t)255;
    return p;
  };
  _Float16* xh   = (_Float16*)alloc((size_t)N_SRC0 * 128 * 2);   // 128 MB
  _Float16* axh  = (_Float16*)alloc((size_t)N_DST0 * 512 * 2);   // 67 MB
  _Float16* h0   = (_Float16*)alloc((size_t)N_DST0 * 256 * 2);   // 33.5 MB
  _Float16* axh1 = (_Float16*)alloc((size_t)N_DST1 * 1024 * 2);  // 16.8 MB
  float* el0     = (float*)alloc((size_t)N_SRC0 * 4 * 4);
  float* er0     = (float*)alloc((size_t)N_DST0 * 4 * 4);
  float* el1     = (float*)alloc((size_t)N_DST0 * 4 * 4);
  float* er1     = (float*)alloc((size_t)N_DST1 * 4 * 4);
  int* seg0      = (int*)alloc((size_t)(N_DST0 + 1) * 4);
  int* seg1      = (int*)alloc((size_t)(N_DST1 + 1) * 4);
  _Float16* BT0  = (_Float16*)alloc(256 * 128 * 2);
  _Float16* BTs  = (_Float16*)alloc(64 * 1024 * 2);
  _Float16* WLR0 = (_Float16*)alloc(16 * 128 * 2);
  _Float16* WLR1 = (_Float16*)alloc(16 * 256 * 2);
  float* wl0     = (float*)alloc(128 * 4 * 4);
  float* wr0     = (float*)alloc(128 * 4 * 4);
  float* wl1     = (float*)alloc(256 * 4 * 4);
  float* wr1     = (float*)alloc(256 * 4 * 4);

  collapse_kernel<<<2, 256, 0, stream>>>(Ws0, al0, wl0, 128, 64);
  collapse_kernel<<<2, 256, 0, stream>>>(Wd0, ar0, wr0, 128, 64);
  collapse_kernel<<<4, 256, 0, stream>>>(Ws1, al1, wl1, 256, 47);
  collapse_kernel<<<4, 256, 0, stream>>>(Wd1, ar1, wr1, 256, 47);
  wlr_stack_kernel<<<8, 256, 0, stream>>>(wl0, wr0, WLR0, 128);
  wlr_stack_kernel<<<16, 256, 0, stream>>>(wl1, wr1, WLR1, 256);
  transposeW_kernel<<<128, 256, 0, stream>>>(Ws0, BT0, 128, 256);
  wstack_kernel<<<256, 256, 0, stream>>>(Ws1, BTs);
  seg_starts_kernel<<<(E0 + 1 + 255) / 256, 256, 0, stream>>>(dst0, E0, N_DST0, seg0);
  seg_starts_kernel<<<(E1 + 1 + 255) / 256, 256, 0, stream>>>(dst1, E1, N_DST1, seg1);
  cvt_elr_mfma_kernel<<<(N_SRC0 + 127) / 128, 256, 0, stream>>>(x, WLR0, xh, el0, er0,
                                                                N_SRC0, N_DST0);
  agg0x_kernel<<<N_DST0, 128, 0, stream>>>(src0, seg0, el0, er0, xh, axh);
  gemm_h0_kernel<<<dim3(4, N_DST0 / 128), 256, 0, stream>>>(axh, BT0, b0, h0);
  el_er1_mfma_kernel<<<N_DST0 / 128, 256, 0, stream>>>(h0, WLR1, el1, er1, N_DST0, N_DST1);
  agg1x_kernel<<<N_DST1, 128, 0, stream>>>(src1, seg1, el1, er1, h0, axh1);
  gemm_out_kernel<<<N_DST1 / 64, 256, 0, stream>>>(axh1, BTs, b1, (float*)d_out);
}